// Round 5
// baseline (341.753 us; speedup 1.0000x reference)
//
#include <hip/hip_runtime.h>

// MeanAggregator: out[b,:] = mean over DISTINCT nbrs[b,:] of features[idx,:]
// features: [N=200000, D=256] f32; nbrs: [B=32768, S=10] int32; out: [B,256] f32
//
// Round 5 — TIMING PROBE: identical round-4 kernel, launched TWICE per
// kernel_launch (idempotent: second launch recomputes the same output).
// Purpose: dur_us has been pinned at ~288us across three structurally
// different kernels, and our dispatch never appears in the rocprof top-5
// (all rows are the harness's 800MB ws-poison fills). The double launch
// disambiguates:
//   dur ~= 288 + small  -> bench time is dominated by harness restore ops;
//                          kernel is already near the ~56us gather roofline.
//   dur ~= 2x288        -> kernel really is ~288us; attack the gather path.

#define AGG_S 10
#define AGG_D 256

typedef float vfloat4 __attribute__((ext_vector_type(4)));

__global__ __launch_bounds__(256) void MeanAggregator_58514634441194_kernel(
    const float* __restrict__ feat,
    const int* __restrict__ nbrs,
    float* __restrict__ out,
    int B)
{
    const int wave = (blockIdx.x * blockDim.x + threadIdx.x) >> 6;  // row id
    const int lane = threadIdx.x & 63;
    if (wave >= B) return;

    const int* __restrict__ row = nbrs + (size_t)wave * AGG_S;
    int idx[AGG_S];
#pragma unroll
    for (int s = 0; s < AGG_S; ++s) idx[s] = __builtin_nontemporal_load(row + s);

    // First-occurrence weights: w[s]=0 iff idx[s] appeared at some j<s.
    float w[AGG_S];
    float cnt = 0.0f;
#pragma unroll
    for (int s = 0; s < AGG_S; ++s) {
        bool dup = false;
#pragma unroll
        for (int j = 0; j < AGG_S; ++j) {
            if (j < s) dup |= (idx[j] == idx[s]);
        }
        w[s] = dup ? 0.0f : 1.0f;
        cnt += w[s];
    }

    // Gather + weighted accumulate: 10 independent 1KB wave reads.
    vfloat4 acc = (vfloat4)(0.0f);
#pragma unroll
    for (int s = 0; s < AGG_S; ++s) {
        const vfloat4* __restrict__ fr =
            (const vfloat4*)(feat + (size_t)idx[s] * AGG_D);
        vfloat4 v = fr[lane];
        acc += w[s] * v;
    }

    acc *= (1.0f / cnt);

    vfloat4* __restrict__ orow = (vfloat4*)(out + (size_t)wave * AGG_D);
    __builtin_nontemporal_store(acc, orow + lane);
}

extern "C" void kernel_launch(void* const* d_in, const int* in_sizes, int n_in,
                              void* d_out, int out_size, void* d_ws, size_t ws_size,
                              hipStream_t stream)
{
    const float* feat = (const float*)d_in[0];
    const int*   nbrs = (const int*)d_in[1];
    float*       out  = (float*)d_out;

    const int B = in_sizes[1] / AGG_S;           // 32768
    const int threads = 256;                     // 4 waves/block, 1 row/wave
    const int rows_per_block = threads / 64;
    const int blocks = (B + rows_per_block - 1) / rows_per_block;

    // PROBE: two identical launches (idempotent). Delta vs round 4 measures
    // the true (warm) kernel duration inside the otherwise-constant bench.
    MeanAggregator_58514634441194_kernel<<<blocks, threads, 0, stream>>>(
        feat, nbrs, out, B);
    MeanAggregator_58514634441194_kernel<<<blocks, threads, 0, stream>>>(
        feat, nbrs, out, B);
}